// Round 6
// baseline (328.755 us; speedup 1.0000x reference)
//
#include <hip/hip_runtime.h>
#include <hip/hip_bf16.h>
#include <math.h>

#define NB 2        // batch
#define NC 64       // channels
#define ND 8        // head dim (C/8)
#define NN 4096     // tokens (T*W*H)
#define NM 256      // landmarks
#define NL 16       // N/M
#define SCALE 0.35355339059327373f  // 1/sqrt(8)
#define PS (NB * NM * NM)           // pair-half stride (floats)

typedef __attribute__((ext_vector_type(4))) float f32x4;
typedef __attribute__((ext_vector_type(8))) short bf16x8;

__device__ inline ushort f2bf(float f) {
  __hip_bfloat16 h = __float2bfloat16(f);
  return *reinterpret_cast<ushort*>(&h);
}
__device__ inline float bf2f(ushort u) {
  return __uint_as_float(((unsigned int)u) << 16);
}

// async global->LDS, 16B per lane; LDS dest must be wave-linear (base + lane*16)
__device__ inline void gl_lds16(const void* g, void* l) {
  __builtin_amdgcn_global_load_lds(
      (const __attribute__((address_space(1))) unsigned int*)g,
      (__attribute__((address_space(3))) unsigned int*)l, 16, 0, 0);
}

// ---------------- qkv projection + fused landmark means ----------------
// grid (80, NN/1024, NB); block 256; each thread 4 consecutive tokens
__global__ __launch_bounds__(256) void qkv2l_kernel(
    const float* __restrict__ x,
    const float* __restrict__ wq, const float* __restrict__ bq,
    const float* __restrict__ wk, const float* __restrict__ bk,
    const float* __restrict__ wv, const float* __restrict__ bv,
    float* __restrict__ q, float* __restrict__ k, float* __restrict__ v,
    float* __restrict__ ql, float* __restrict__ kl) {
  __shared__ float ws[NC];
  int o = blockIdx.x;            // 0..79: 0-7 q, 8-15 k, 16-79 v
  int b = blockIdx.z;
  int n0 = blockIdx.y * 1024;
  int t = threadIdx.x;
  const float* wrow;
  float bias;
  if (o < ND)            { wrow = wq + (size_t)o * NC;            bias = bq[o]; }
  else if (o < 2 * ND)   { wrow = wk + (size_t)(o - ND) * NC;     bias = bk[o - ND]; }
  else                   { wrow = wv + (size_t)(o - 2 * ND) * NC; bias = bv[o - 2 * ND]; }
  if (t < NC) ws[t] = wrow[t];
  __syncthreads();
  int n = n0 + t * 4;
  float4 acc = {bias, bias, bias, bias};
  #pragma unroll
  for (int c = 0; c < NC; ++c) {
    float wc = ws[c];
    float4 xv = *(const float4*)(x + ((size_t)b * NC + c) * NN + n);
    acc.x += wc * xv.x; acc.y += wc * xv.y; acc.z += wc * xv.z; acc.w += wc * xv.w;
  }
  if (o < ND) {
    float* qp = q + ((size_t)b * NN + n) * ND + o;
    qp[0] = acc.x; qp[8] = acc.y; qp[16] = acc.z; qp[24] = acc.w;
  } else if (o < 2 * ND) {
    float* kp = k + ((size_t)b * NN + n) * ND + (o - ND);
    kp[0] = acc.x; kp[8] = acc.y; kp[16] = acc.z; kp[24] = acc.w;
  } else {
    *(float4*)(v + ((size_t)b * NC + (o - 2 * ND)) * NN + n) = acc;
  }
  // fused landmark: group of 16 tokens = 4 consecutive threads (wave-aligned quads)
  if (o < 2 * ND) {
    float s4 = acc.x + acc.y + acc.z + acc.w;
    s4 += __shfl_xor(s4, 1);
    s4 += __shfl_xor(s4, 2);
    if ((t & 3) == 0) {
      int g = n0 / 16 + (t >> 2);
      float* dst = (o < ND) ? ql : kl;
      dst[((size_t)b * NM + g) * ND + (o & 7)] = s4 * (1.0f / 16.0f);
    }
  }
}

// ---------------- merged softmaxes (k1 bf16, k2 f32, k3 f32) + kv zero ----------------
__global__ __launch_bounds__(256) void scores_all_kernel(
    const float* __restrict__ q, const float* __restrict__ ql,
    const float* __restrict__ kw, const float* __restrict__ kl,
    ushort* __restrict__ k1bf, float* __restrict__ k2w,
    float* __restrict__ k3w, float* __restrict__ kvw) {
  __shared__ float skl[NM][9];
  __shared__ float wred[4], wsum[4];
  int blk = blockIdx.x;
  int t = threadIdx.x;
  if (blk < 2048 + 128) {
    // ---- softmax_m body: rows of Q vs landmark keys ----
    const float* Q; int R, b, xrow;
    bool isbf;
    if (blk < 2048) { b = blk >> 10; xrow = blk & 1023; Q = q;  R = NN; isbf = true; }
    else { int r = blk - 2048; b = r >> 6; xrow = r & 63; Q = ql; R = NM; isbf = false; }
    for (int i = t; i < NM * ND; i += 256) skl[i >> 3][i & 7] = kl[(size_t)b * NM * ND + i];
    __syncthreads();
    int wave = t >> 6, lane = t & 63;
    int r = xrow * 4 + wave;
    const float* qrow = Q + ((size_t)b * R + r) * ND;
    float qr[ND];
    #pragma unroll
    for (int dd = 0; dd < ND; ++dd) qr[dd] = qrow[dd];
    float sc[4];
    float lmax = -1e30f;
    #pragma unroll
    for (int s = 0; s < 4; ++s) {
      int j = lane + 64 * s;
      float a = 0.f;
      #pragma unroll
      for (int dd = 0; dd < ND; ++dd) a += qr[dd] * skl[j][dd];
      sc[s] = a * SCALE;
      lmax = fmaxf(lmax, sc[s]);
    }
    for (int off = 32; off; off >>= 1) lmax = fmaxf(lmax, __shfl_xor(lmax, off));
    float lsum = 0.f;
    #pragma unroll
    for (int s = 0; s < 4; ++s) { sc[s] = expf(sc[s] - lmax); lsum += sc[s]; }
    for (int off = 32; off; off >>= 1) lsum += __shfl_xor(lsum, off);
    float inv = 1.0f / lsum;
    if (isbf) {
      #pragma unroll
      for (int s = 0; s < 4; ++s)
        k1bf[((size_t)b * R + r) * NM + lane + 64 * s] = f2bf(sc[s] * inv);
    } else {
      #pragma unroll
      for (int s = 0; s < 4; ++s)
        k2w[((size_t)b * R + r) * NM + lane + 64 * s] = sc[s] * inv;
    }
  } else if (blk < 2048 + 128 + 512) {
    // ---- k3 softmax: landmark queries vs all keys ----
    int r = blk - 2176;
    int b = r >> 8, i = r & 255;
    float qr[ND];
    #pragma unroll
    for (int dd = 0; dd < ND; ++dd) qr[dd] = ql[((size_t)b * NM + i) * ND + dd];
    float sc[16];
    float lmax = -1e30f;
    #pragma unroll
    for (int s = 0; s < 16; ++s) {
      int n = t + 256 * s;
      const float* kp = kw + ((size_t)b * NN + n) * ND;
      float a = 0.f;
      #pragma unroll
      for (int dd = 0; dd < ND; ++dd) a += qr[dd] * kp[dd];
      sc[s] = a * SCALE;
      lmax = fmaxf(lmax, sc[s]);
    }
    for (int off = 32; off; off >>= 1) lmax = fmaxf(lmax, __shfl_xor(lmax, off));
    if ((t & 63) == 0) wred[t >> 6] = lmax;
    __syncthreads();
    lmax = fmaxf(fmaxf(wred[0], wred[1]), fmaxf(wred[2], wred[3]));
    float lsum = 0.f;
    #pragma unroll
    for (int s = 0; s < 16; ++s) { sc[s] = expf(sc[s] - lmax); lsum += sc[s]; }
    for (int off = 32; off; off >>= 1) lsum += __shfl_xor(lsum, off);
    if ((t & 63) == 0) wsum[t >> 6] = lsum;
    __syncthreads();
    lsum = wsum[0] + wsum[1] + wsum[2] + wsum[3];
    float inv = 1.0f / lsum;
    #pragma unroll
    for (int s = 0; s < 16; ++s) k3w[((size_t)b * NM + i) * NN + t + 256 * s] = sc[s] * inv;
  } else {
    // ---- kv zero ----
    int r = blk - 2688;
    kvw[r * 256 + t] = 0.0f;
  }
}

// ---------------- denom (max colsum) + k3 -> k3T bf16 transpose ----------------
__global__ __launch_bounds__(256) void denom_k3t_kernel(
    const float* __restrict__ k2, float* __restrict__ denw,
    const float* __restrict__ k3, ushort* __restrict__ k3t) {
  __shared__ float red[256];
  __shared__ float tile[32][33];
  int blk = blockIdx.x;
  int t = threadIdx.x;
  if (blk < NB) {
    int b = blk;
    float cs = 0.f;
    for (int i = 0; i < NM; ++i) cs += k2[((size_t)b * NM + i) * NM + t];
    red[t] = cs;
    __syncthreads();
    for (int off = 128; off; off >>= 1) {
      if (t < off) red[t] = fmaxf(red[t], red[t + off]);
      __syncthreads();
    }
    if (t == 0) denw[b] = red[0];
  } else {
    int r = blk - NB;
    int n0 = (r & 127) * 32, m0 = ((r >> 7) & 7) * 32, b = r >> 10;
    int rr = t >> 3, c4 = (t & 7) * 4;
    float4 v = *(const float4*)(k3 + ((size_t)b * NM + m0 + rr) * NN + n0 + c4);
    tile[c4][rr] = v.x; tile[c4 + 1][rr] = v.y; tile[c4 + 2][rr] = v.z; tile[c4 + 3][rr] = v.w;
    __syncthreads();
    ushort4 u;
    u.x = f2bf(tile[rr][c4]);     u.y = f2bf(tile[rr][c4 + 1]);
    u.z = f2bf(tile[rr][c4 + 2]); u.w = f2bf(tile[rr][c4 + 3]);
    *(ushort4*)(k3t + ((size_t)b * NN + n0 + rr) * NM + m0 + c4) = u;
  }
}

// ---------------- NS GEMM: split-K half-pair outputs, t=4 micro-tile ----------------
// O(slice) = s_ab * partial(A@B over K-half) ; slice0 additionally += s_a * A_full
// amode/bmode: 0 = plain matrix, 1 = split pair (sum halves), 2 = virtual V0 = k2^T*dval
__global__ __launch_bounds__(64) void ns_gemm(
    const float* __restrict__ A, int amode,
    const float* __restrict__ B, int bmode,
    const float* __restrict__ denw, float* __restrict__ O,
    float s_a, float s_ab) {
  __shared__ float As[128][36];   // [k][row]
  __shared__ float Bs[128][36];   // [k][col]
  int t = threadIdx.x;
  int bj = blockIdx.x * 32, bi = blockIdx.y * 32;
  int b = blockIdx.z >> 1, slice = blockIdx.z & 1;
  int k0 = slice * 128;
  size_t bo = (size_t)b * NM * NM;
  float dval = (amode == 2 || bmode == 2) ? 1.0f / fmaxf(denw[0], denw[1]) : 0.f;
  // stage A panel: As[k][r] = Afull[bi+r][k0+k]
  {
    int r = t >> 1, kc0 = (t & 1) * 64;
    if (amode == 2) {
      for (int i = 0; i < 64; ++i) {
        int kk = kc0 + i;
        As[kk][r] = A[bo + (size_t)(k0 + kk) * NM + bi + r] * dval;
      }
    } else if (amode == 1) {
      for (int i = 0; i < 16; ++i) {
        const float* p = A + bo + (size_t)(bi + r) * NM + k0 + kc0 + i * 4;
        float4 v0 = *(const float4*)p;
        float4 v1 = *(const float4*)(p + PS);
        As[kc0 + i * 4 + 0][r] = v0.x + v1.x;
        As[kc0 + i * 4 + 1][r] = v0.y + v1.y;
        As[kc0 + i * 4 + 2][r] = v0.z + v1.z;
        As[kc0 + i * 4 + 3][r] = v0.w + v1.w;
      }
    } else {
      for (int i = 0; i < 16; ++i) {
        float4 v0 = *(const float4*)(A + bo + (size_t)(bi + r) * NM + k0 + kc0 + i * 4);
        As[kc0 + i * 4 + 0][r] = v0.x;
        As[kc0 + i * 4 + 1][r] = v0.y;
        As[kc0 + i * 4 + 2][r] = v0.z;
        As[kc0 + i * 4 + 3][r] = v0.w;
      }
    }
    // stage B panel: Bs[k][c] = Bfull[k0+k][bj+c]
    if (bmode == 2) {
      for (int i2 = 0; i2 < 2; ++i2) {
        int kr = t + 64 * i2;
        for (int c = 0; c < 32; ++c)
          Bs[kr][c] = B[bo + (size_t)(bj + c) * NM + k0 + kr] * dval;
      }
    } else if (bmode == 1) {
      for (int i2 = 0; i2 < 2; ++i2) {
        int kr = t + 64 * i2;
        for (int c4 = 0; c4 < 32; c4 += 4) {
          const float* p = B + bo + (size_t)(k0 + kr) * NM + bj + c4;
          float4 v0 = *(const float4*)p;
          float4 v1 = *(const float4*)(p + PS);
          v0.x += v1.x; v0.y += v1.y; v0.z += v1.z; v0.w += v1.w;
          *(float4*)&Bs[kr][c4] = v0;
        }
      }
    } else {
      for (int i2 = 0; i2 < 2; ++i2) {
        int kr = t + 64 * i2;
        for (int c4 = 0; c4 < 32; c4 += 4)
          *(float4*)&Bs[kr][c4] =
              *(const float4*)(B + bo + (size_t)(k0 + kr) * NM + bj + c4);
      }
    }
  }
  __syncthreads();
  int tx = t & 7, ty = t >> 3;
  float acc[4][4] = {};
  #pragma unroll 4
  for (int kk = 0; kk < 128; ++kk) {
    float4 a4 = *(const float4*)&As[kk][ty * 4];
    float4 b4 = *(const float4*)&Bs[kk][tx * 4];
    float av[4] = {a4.x, a4.y, a4.z, a4.w};
    float bv[4] = {b4.x, b4.y, b4.z, b4.w};
    #pragma unroll
    for (int i = 0; i < 4; ++i)
      #pragma unroll
      for (int j = 0; j < 4; ++j) acc[i][j] += av[i] * bv[j];
  }
  float* Op = O + (size_t)slice * PS + bo;
  bool addA = (slice == 0) && (s_a != 0.0f);
  #pragma unroll
  for (int i = 0; i < 4; ++i) {
    int row = bi + ty * 4 + i;
    float4 rv;
    rv.x = s_ab * acc[i][0]; rv.y = s_ab * acc[i][1];
    rv.z = s_ab * acc[i][2]; rv.w = s_ab * acc[i][3];
    if (addA) {
      int col = bj + tx * 4;
      if (amode == 2) {
        rv.x += s_a * A[bo + (size_t)(col + 0) * NM + row] * dval;
        rv.y += s_a * A[bo + (size_t)(col + 1) * NM + row] * dval;
        rv.z += s_a * A[bo + (size_t)(col + 2) * NM + row] * dval;
        rv.w += s_a * A[bo + (size_t)(col + 3) * NM + row] * dval;
      } else if (amode == 1) {
        const float* p = A + bo + (size_t)row * NM + col;
        float4 a0 = *(const float4*)p;
        float4 a1 = *(const float4*)(p + PS);
        rv.x += s_a * (a0.x + a1.x); rv.y += s_a * (a0.y + a1.y);
        rv.z += s_a * (a0.z + a1.z); rv.w += s_a * (a0.w + a1.w);
      } else {
        float4 a0 = *(const float4*)(A + bo + (size_t)row * NM + col);
        rv.x += s_a * a0.x; rv.y += s_a * a0.y;
        rv.z += s_a * a0.z; rv.w += s_a * a0.w;
      }
    }
    *(float4*)(Op + (size_t)row * NM + bj + tx * 4) = rv;
  }
}

// ---------------- Vinv pair -> bf16 transposed ----------------
__global__ __launch_bounds__(256) void cvt_vinv_kernel(const float* __restrict__ Vp,
                                                       ushort* __restrict__ Vt) {
  int b = blockIdx.z;
  int n0 = blockIdx.x * 32, m0 = blockIdx.y * 32;
  __shared__ float tile[32][33];
  int t = threadIdx.x;
  int r = t >> 3, c4 = (t & 7) * 4;
  size_t bo = (size_t)b * NM * NM;
  const float* p = Vp + bo + (size_t)(m0 + r) * NM + n0 + c4;
  float4 v0 = *(const float4*)p;
  float4 v1 = *(const float4*)(p + PS);
  tile[c4][r] = v0.x + v1.x; tile[c4 + 1][r] = v0.y + v1.y;
  tile[c4 + 2][r] = v0.z + v1.z; tile[c4 + 3][r] = v0.w + v1.w;
  __syncthreads();
  ushort4 u;
  u.x = f2bf(tile[r][c4]);     u.y = f2bf(tile[r][c4 + 1]);
  u.z = f2bf(tile[r][c4 + 2]); u.w = f2bf(tile[r][c4 + 3]);
  *(ushort4*)(Vt + bo + (size_t)(n0 + r) * NM + m0 + c4) = u;
}

// ---------------- A = k1 @ Vinv via bf16 MFMA (global_load_lds staging) ----------------
__global__ __launch_bounds__(256) void gemm_a_mfma(
    const ushort* __restrict__ k1bf, const ushort* __restrict__ Vt,
    ushort* __restrict__ Abf) {
  int b = blockIdx.z;
  int bi = blockIdx.y * 128, bj = blockIdx.x * 128;
  __shared__ ushort As[128 * 64];
  __shared__ ushort Bs[128 * 64];
  int t = threadIdx.x;
  int wave = t >> 6, lane = t & 63;
  int wr = wave >> 1, wc = wave & 1;
  const ushort* Ab = k1bf + (size_t)b * NN * NM;
  const ushort* Bb = Vt + (size_t)b * NM * NM;
  f32x4 acc[4][4] = {};
  for (int k0 = 0; k0 < NM; k0 += 64) {
    #pragma unroll
    for (int q = 0; q < 4; ++q) {
      int s = q * 256 + t;
      int r = s >> 3, c = s & 7;
      int cs = (c ^ (r & 7)) << 3;
      gl_lds16(Ab + (size_t)(bi + r) * NM + k0 + cs, As + (size_t)s * 8);
      gl_lds16(Bb + (size_t)(bj + r) * NM + k0 + cs, Bs + (size_t)s * 8);
    }
    __syncthreads();
    #pragma unroll
    for (int kk = 0; kk < 2; ++kk) {
      int koff = kk * 64 + (lane >> 4) * 16;
      bf16x8 af[4], bfv[4];
      #pragma unroll
      for (int mi = 0; mi < 4; ++mi) {
        int row = wr * 64 + mi * 16 + (lane & 15);
        af[mi] = *(const bf16x8*)((const char*)As + row * 128 + (koff ^ ((row & 7) << 4)));
      }
      #pragma unroll
      for (int nj = 0; nj < 4; ++nj) {
        int row = wc * 64 + nj * 16 + (lane & 15);
        bfv[nj] = *(const bf16x8*)((const char*)Bs + row * 128 + (koff ^ ((row & 7) << 4)));
      }
      #pragma unroll
      for (int mi = 0; mi < 4; ++mi)
        #pragma unroll
        for (int nj = 0; nj < 4; ++nj)
          acc[mi][nj] = __builtin_amdgcn_mfma_f32_16x16x32_bf16(af[mi], bfv[nj], acc[mi][nj], 0, 0, 0);
    }
    __syncthreads();
  }
  int col = lane & 15, rbase = (lane >> 4) * 4;
  #pragma unroll
  for (int mi = 0; mi < 4; ++mi)
    #pragma unroll
    for (int nj = 0; nj < 4; ++nj)
      #pragma unroll
      for (int r = 0; r < 4; ++r)
        Abf[((size_t)b * NN + bi + wr * 64 + mi * 16 + rbase + r) * NM
            + bj + wc * 64 + nj * 16 + col] = f2bf(acc[mi][nj][r]);
}

// ---------------- merged: attn = A @ k3 (bf16 MFMA, XCD swizzle) + split-K kv ----------------
__global__ __launch_bounds__(256) void attn_kv_kernel(
    const ushort* __restrict__ Abf, const ushort* __restrict__ K3T,
    float* __restrict__ attn, const float* __restrict__ k3w,
    const float* __restrict__ vw, float* __restrict__ kvw) {
  __shared__ char smem[32768];
  int blk = blockIdx.x;
  int t = threadIdx.x;
  if (blk < 2048) {
    // ---- attn ----
    ushort* As = (ushort*)smem;
    ushort* Bs = (ushort*)(smem + 16384);
    int swz = (blk & 7) * 256 + (blk >> 3);   // bijective XCD swizzle (2048 % 8 == 0)
    int b = swz >> 10;
    int rem = swz & 1023;
    int bi = (rem >> 5) * 128, bj = (rem & 31) * 128;
    int wave = t >> 6, lane = t & 63;
    int wr = wave >> 1, wc = wave & 1;
    const ushort* Ab = Abf + (size_t)b * NN * NM;
    const ushort* Bb = K3T + (size_t)b * NN * NM;
    f32x4 acc[4][4] = {};
    for (int k0 = 0; k0 < NM; k0 += 64) {
      #pragma unroll
      for (int q = 0; q < 4; ++q) {
        int s = q * 256 + t;
        int r = s >> 3, c = s & 7;
        int cs = (c ^ (r & 7)) << 3;
        gl_lds16(Ab + (size_t)(bi + r) * NM + k0 + cs, As + (size_t)s * 8);
        gl_lds16(Bb + (size_t)(bj + r) * NM + k0 + cs, Bs + (size_t)s * 8);
      }
      __syncthreads();
      #pragma unroll
      for (int kk = 0; kk < 2; ++kk) {
        int koff = kk * 64 + (lane >> 4) * 16;
        bf16x8 af[4], bfv[4];
        #pragma unroll
        for (int mi = 0; mi < 4; ++mi) {
          int row = wr * 64 + mi * 16 + (lane & 15);
          af[mi] = *(const bf16x8*)((const char*)As + row * 128 + (koff ^ ((row & 7) << 4)));
        }
        #pragma unroll
        for (int nj = 0; nj < 4; ++nj) {
          int row = wc * 64 + nj * 16 + (lane & 15);
          bfv[nj] = *(const bf16x8*)((const char*)Bs + row * 128 + (koff ^ ((row & 7) << 4)));
        }
        #pragma unroll
        for (int mi = 0; mi < 4; ++mi)
          #pragma unroll
          for (int nj = 0; nj < 4; ++nj)
            acc[mi][nj] = __builtin_amdgcn_mfma_f32_16x16x32_bf16(af[mi], bfv[nj], acc[mi][nj], 0, 0, 0);
      }
      __syncthreads();
    }
    int col = lane & 15, rbase = (lane >> 4) * 4;
    #pragma unroll
    for (int mi = 0; mi < 4; ++mi)
      #pragma unroll
      for (int nj = 0; nj < 4; ++nj)
        #pragma unroll
        for (int r = 0; r < 4; ++r)
          attn[((size_t)b * NN + bi + wr * 64 + mi * 16 + rbase + r) * NN
               + bj + wc * 64 + nj * 16 + col] = acc[mi][nj][r];
  } else {
    // ---- kv split-K ----
    typedef float KVRow[33];
    KVRow* Ks = (KVRow*)smem;
    KVRow* Vs = (KVRow*)(smem + 64 * 33 * 4);
    int r = blk - 2048;
    int bp = (r & 3) * 64;
    int jsl = (r >> 2) & 31;
    int b = r >> 7;
    int j0base = jsl * (NN / 32);
    int tx = t & 15, ty = t >> 4;
    int lrow = t >> 2, ljc = (t & 3) * 8;
    float acc[4][4] = {};
    for (int j0 = j0base; j0 < j0base + NN / 32; j0 += 32) {
      float4 a0 = *(const float4*)(k3w + ((size_t)b * NM + bp + lrow) * NN + j0 + ljc);
      float4 a1 = *(const float4*)(k3w + ((size_t)b * NM + bp + lrow) * NN + j0 + ljc + 4);
      float4 v0 = *(const float4*)(vw + ((size_t)b * NC + lrow) * NN + j0 + ljc);
      float4 v1 = *(const float4*)(vw + ((size_t)b * NC + lrow) * NN + j0 + ljc + 4);
      Ks[lrow][ljc + 0] = a0.x; Ks[lrow][ljc + 1] = a0.y; Ks[lrow][ljc + 2] = a0.z; Ks[lrow][ljc + 3] = a0.w;
      Ks[lrow][ljc + 4] = a1.x; Ks[lrow][ljc + 5] = a1.y; Ks[lrow][ljc + 6] = a1.z; Ks[lrow][ljc + 7] = a1.w;
      Vs[lrow][ljc + 0] = v0.x; Vs[lrow][ljc + 1] = v0.y; Vs[lrow][ljc + 2] = v0.z; Vs[lrow][ljc + 3] = v0.w;
      Vs[lrow][ljc + 4] = v1.x; Vs[lrow][ljc + 5] = v1.y; Vs[lrow][ljc + 6] = v1.z; Vs[lrow][ljc + 7] = v1.w;
      __syncthreads();
      #pragma unroll
      for (int kk = 0; kk < 32; ++kk) {
        float av_[4], bv_[4];
        #pragma unroll
        for (int i = 0; i < 4; ++i) av_[i] = Ks[(ty << 2) + i][kk];
        #pragma unroll
        for (int j = 0; j < 4; ++j) bv_[j] = Vs[(tx << 2) + j][kk];
        #pragma unroll
        for (int i = 0; i < 4; ++i)
          #pragma unroll
          for (int j = 0; j < 4; ++j) acc[i][j] += av_[i] * bv_[j];
      }
      __syncthreads();
    }
    #pragma unroll
    for (int i = 0; i < 4; ++i)
      #pragma unroll
      for (int j = 0; j < 4; ++j)
        atomicAdd(&kvw[((size_t)b * NM + bp + (ty << 2) + i) * NC + (tx << 2) + j], acc[i][j]);
  }
}

// ---------------- out = gamma*(A@kv) + x  (A in bf16) ----------------
__global__ __launch_bounds__(256) void out_kernel(
    const ushort* __restrict__ Abf, const float* __restrict__ kvm,
    const float* __restrict__ x, const float* __restrict__ gamma,
    float* __restrict__ outp) {
  __shared__ float As[32 * 256];
  int blk = blockIdx.x;
  int b = blk / (NN / 32), n0 = (blk % (NN / 32)) * 32;
  int t = threadIdx.x;
  for (int it = 0; it < 32; ++it)
    As[it * 256 + (t ^ (it & 31))] = bf2f(Abf[((size_t)b * NN + n0 + it) * NM + t]);
  __syncthreads();
  int tn = t & 31, cg0 = (t >> 5) * 8;
  float g = gamma[0];
  float acc[8] = {};
  for (int p = 0; p < NM; ++p) {
    float a = As[tn * 256 + (p ^ (tn & 31))];
    float4 kv0 = *(const float4*)(kvm + ((size_t)b * NM + p) * NC + cg0);
    float4 kv1 = *(const float4*)(kvm + ((size_t)b * NM + p) * NC + cg0 + 4);
    acc[0] += a * kv0.x; acc[1] += a * kv0.y; acc[2] += a * kv0.z; acc[3] += a * kv0.w;
    acc[4] += a * kv1.x; acc[5] += a * kv1.y; acc[6] += a * kv1.z; acc[7] += a * kv1.w;
  }
  #pragma unroll
  for (int qd = 0; qd < 8; ++qd) {
    int c = cg0 + qd;
    size_t idx = ((size_t)b * NC + c) * NN + n0 + tn;
    outp[idx] = g * acc[qd] + x[idx];
  }
}

extern "C" void kernel_launch(void* const* d_in, const int* in_sizes, int n_in,
                              void* d_out, int out_size, void* d_ws, size_t ws_size,
                              hipStream_t stream) {
  const float* x     = (const float*)d_in[0];
  const float* wq    = (const float*)d_in[1];
  const float* bq    = (const float*)d_in[2];
  const float* wk    = (const float*)d_in[3];
  const float* bk    = (const float*)d_in[4];
  const float* wv    = (const float*)d_in[5];
  const float* bv    = (const float*)d_in[6];
  const float* gamma = (const float*)d_in[7];
  float* outp = (float*)d_out;                       // [B][C][N]
  float* attn = outp + (size_t)NB * NC * NN;         // [B][N][N]
  float* w = (float*)d_ws;

  float* qw   = w;                 // [B][N][D]    65536
  float* kw   = qw + 65536;        // [B][N][D]    65536
  float* vw   = kw + 65536;        // [B][C][N]    524288
  float* qlw  = vw + 524288;       // [B][M][D]    4096
  float* klw  = qlw + 4096;        // [B][M][D]    4096
  float* k1w  = klw + 4096;        // 8 MB region: k1bf (4MB) + k3T (4MB)
  float* k2w  = k1w + 2097152;     // [B][M][M]    131072
  float* k3w  = k2w + 131072;      // [B][M][N]    2097152
  float* Abuf = k3w + 2097152;     // 4 MB region: Abf bf16
  float* Zp   = Abuf + 1048576;    // pair 262144
  float* T1p  = Zp + 2 * PS;       // pair 262144
  float* T2p  = T1p + 2 * PS;      // pair 262144
  float* Vap  = T2p + 2 * PS;      // pair 262144
  float* Vbp  = Vap + 2 * PS;      // pair 262144
  float* kvw  = Vbp + 2 * PS;      // [B][M][C]    32768
  float* denw = kvw + 32768;       // [2]
  ushort* k1bf  = (ushort*)k1w;                 // [B][N][M] bf16
  ushort* k3T   = (ushort*)k1w + 2097152;       // [B][N][M] bf16 (k3^T)
  ushort* Abf   = (ushort*)Abuf;                // [B][N][M] bf16
  ushort* Vinvt = (ushort*)Zp;                  // [B][M][M] bf16, after NS (Zp dead)

  qkv2l_kernel<<<dim3(80, NN / 1024, NB), dim3(256), 0, stream>>>(
      x, wq, bq, wk, bk, wv, bv, qw, kw, vw, qlw, klw);
  scores_all_kernel<<<dim3(2048 + 128 + 512 + 128), dim3(256), 0, stream>>>(
      qw, qlw, kw, klw, k1bf, k2w, k3w, kvw);
  denom_k3t_kernel<<<dim3(NB + 2048), dim3(256), 0, stream>>>(k2w, denw, k3w, k3T);

  // Newton-Schulz: 24 launches, split-K half-pair outputs, V0 virtualized
  const float* Vptr = k2w; int vmode = 2;
  float* Vout = Vap;
  float* Vfin = nullptr;
  for (int it = 0; it < 6; ++it) {
    ns_gemm<<<dim3(8, 8, NB * 2), dim3(64), 0, stream>>>(k2w, 0, Vptr, vmode, denw, Zp, 0.f, 1.f);
    ns_gemm<<<dim3(8, 8, NB * 2), dim3(64), 0, stream>>>(Zp, 1, Zp, 1, denw, T1p, 7.f, -1.f);
    ns_gemm<<<dim3(8, 8, NB * 2), dim3(64), 0, stream>>>(Zp, 1, T1p, 1, denw, T2p, 15.f, -1.f);
    ns_gemm<<<dim3(8, 8, NB * 2), dim3(64), 0, stream>>>(Vptr, vmode, T2p, 1, denw, Vout, 3.25f, -0.25f);
    Vfin = Vout;
    Vptr = Vout; vmode = 1;
    Vout = (Vout == Vap) ? Vbp : Vap;
  }

  cvt_vinv_kernel<<<dim3(NM / 32, NM / 32, NB), dim3(256), 0, stream>>>(Vfin, Vinvt);
  gemm_a_mfma<<<dim3(NM / 128, NN / 128, NB), dim3(256), 0, stream>>>(k1bf, Vinvt, Abf);
  attn_kv_kernel<<<dim3(2048 + 256), dim3(256), 0, stream>>>(Abf, k3T, attn, k3w, vw, kvw);
  out_kernel<<<dim3(NB * NN / 32), dim3(256), 0, stream>>>(Abf, kvw, x, gamma, outp);
}